// Round 8
// baseline (186.306 us; speedup 1.0000x reference)
//
#include <hip/hip_runtime.h>
#include <hip/hip_bf16.h>
#include <hip/hip_cooperative_groups.h>

namespace cg = cooperative_groups;

// B=32, T=4096, F=16, L=2047, n=8192, 256 output freqs.
// Math: s[b,t] = sum_f x[b,t,f]; r[b,tau] = sum_t s[t]*s[t+tau] (tau=0..2048)
// G[b,m] = (A[m]/16384) * exp(-2*pi*i*2047*m/4096),
// A[m] = r[0] + 2*sum_{j=1}^{2047} r[j]*cos(2*pi*m*j/4096) + (-1)^m r[2048].
// Output layout (verified R3): PLANAR — Re at [b*256+m], Im at [8192+b*256+m].
// R8: single cooperative kernel (3 dispatches -> 1); phases separated by
//     grid.sync(). Phase bodies are the R7-verified ksum/kautoc/kdft.

#define B_DIM 32
#define T_DIM 4096
#define NLAG 2049
#define NCHUNK 16
#define TS (T_DIM / NCHUNK)            // 256
#define LOGI 2304                      // staged window: (TS-8)+2040+15 = 2303 max
#define PSTRIDE 2052                   // partial row stride (16B-aligned)
#define THETA 1.5339807878856412e-03f  // 2*pi/4096

// LDS swizzle: +4 floats pad every 32. Preserves 16B alignment/contiguity for
// l%4==0 accesses; makes stride-8-floats/lane window reads conflict-cheap.
#define SW(l) ((l) + (((l) >> 5) << 2))
#define LS_PHYS 2592                   // SW(2303)=2587; also >= NLAG for phase 3

__global__ __launch_bounds__(256) void kfused(const float* __restrict__ x,
                                              float* __restrict__ s,
                                              float* __restrict__ part,
                                              float* __restrict__ out) {
    cg::grid_group gg = cg::this_grid();
    __shared__ __align__(16) float ls[LS_PHYS];
    int tid = threadIdx.x;
    int blk = blockIdx.x;                            // 0..511

    // ---------------- Phase 1: s[b,t] = sum_f x[b,t,f] ----------------
    {
        int i = blk * 256 + tid;                     // 0..131071 = b*4096+t
        const float4* xv = (const float4*)(x + (size_t)i * 16);
        float4 a = xv[0], b = xv[1], c = xv[2], d = xv[3];
        s[i] = ((a.x + a.y) + (a.z + a.w)) + ((b.x + b.y) + (b.z + b.w)) +
               ((c.x + c.y) + (c.z + c.w)) + ((d.x + d.y) + (d.z + d.w));
    }
    gg.sync();

    // ---------------- Phase 2: balanced register-tiled autocorr ----------------
    // block (b,q) stages s[t0 .. t0+2304) zero-extended; every thread runs the
    // SAME 32 branch-free iterations (8 t's x 8 lags); zeros kill out-of-range.
    {
        int b = blk >> 4;
        int q = blk & 15;
        int t0 = q * TS;
        const float* sb = s + (size_t)b * T_DIM;
        for (int idx = tid; idx < LOGI / 4; idx += 256) {
            int l = idx * 4;
            int g = t0 + l;                          // 4-aligned
            float4 v = make_float4(0.f, 0.f, 0.f, 0.f);
            if (g < T_DIM) v = *(const float4*)&sb[g];
            *(float4*)&ls[SW(l)] = v;                // zero-extended tail
        }
        __syncthreads();

        float* pr = part + ((size_t)b * NCHUNK + q) * PSTRIDE;
        int tau0 = tid * 8;                          // 0..2040

        float acc[8] = {0.f, 0.f, 0.f, 0.f, 0.f, 0.f, 0.f, 0.f};
        float w[16];
        {
            float4 w0 = *(const float4*)&ls[SW(tau0)];
            float4 w1 = *(const float4*)&ls[SW(tau0 + 4)];
            w[0] = w0.x; w[1] = w0.y; w[2] = w0.z; w[3] = w0.w;
            w[4] = w1.x; w[5] = w1.y; w[6] = w1.z; w[7] = w1.w;
        }
        #pragma unroll 4
        for (int t = 0; t < TS; t += 8) {            // 32 uniform iterations
            int ln = t + tau0 + 8;
            float4 n0 = *(const float4*)&ls[SW(ln)];
            float4 n1 = *(const float4*)&ls[SW(ln + 4)];
            w[8] = n0.x;  w[9] = n0.y;  w[10] = n0.z; w[11] = n0.w;
            w[12] = n1.x; w[13] = n1.y; w[14] = n1.z; w[15] = n1.w;
            float4 a0 = *(const float4*)&ls[SW(t)];  // wave-uniform -> broadcast
            float4 a1 = *(const float4*)&ls[SW(t + 4)];
            float as[8] = {a0.x, a0.y, a0.z, a0.w, a1.x, a1.y, a1.z, a1.w};
            #pragma unroll
            for (int s2 = 0; s2 < 8; ++s2) {
                #pragma unroll
                for (int u = 0; u < 8; ++u)
                    acc[u] = fmaf(as[s2], w[s2 + u], acc[u]);
            }
            #pragma unroll
            for (int k = 0; k < 8; ++k) w[k] = w[k + 8];
        }
        *(float4*)&pr[tau0]     = make_float4(acc[0], acc[1], acc[2], acc[3]);
        *(float4*)&pr[tau0 + 4] = make_float4(acc[4], acc[5], acc[6], acc[7]);

        // lag 2048: wave 3, branch-free over staged (zero-extended) window
        if (tid >= 192) {
            int sl = tid - 192;
            float a2 = 0.f;
            #pragma unroll
            for (int t = 0; t < TS; t += 64)
                a2 += ls[SW(t + sl)] * ls[SW(t + sl + 2048)];
            for (int off = 32; off; off >>= 1) a2 += __shfl_down(a2, off, 64);
            if (tid == 192) pr[2048] = a2;
        }
    }
    gg.sync();

    // ---------------- Phase 3: partial-reduce + DFT (blocks 0..255) ----------------
    if (blk < 256) {
        int b = blk >> 3;                            // 0..31
        int g = blk & 7;                             // 0..7 -> 32 m's per block
        const float* pb = part + (size_t)b * NCHUNK * PSTRIDE;
        for (int idx = tid; idx < 512; idx += 256) { // tau 0..2047 as float4
            float4 acc = make_float4(0.f, 0.f, 0.f, 0.f);
            #pragma unroll
            for (int q = 0; q < NCHUNK; ++q) {
                float4 v = *(const float4*)&pb[(size_t)q * PSTRIDE + idx * 4];
                acc.x += v.x; acc.y += v.y; acc.z += v.z; acc.w += v.w;
            }
            *(float4*)&ls[idx * 4] = acc;            // reuse ls as r[b, 0..2047]
        }
        if (tid == 0) {                              // tau = 2048
            float acc = 0.f;
            #pragma unroll
            for (int q = 0; q < NCHUNK; ++q)
                acc += pb[(size_t)q * PSTRIDE + 2048];
            ls[2048] = acc;
        }
        __syncthreads();

        int m = g * 32 + (tid >> 3);
        int slice = tid & 7;
        float partsum = 0.0f;
        #pragma unroll 8
        for (int k = 0; k < 256; ++k) {              // j = slice + 8k in 0..2047
            int j = slice + (k << 3);
            int p = (m * j) & 4095;                  // exact integer phase
            partsum = fmaf(ls[j], __cosf((float)p * THETA), partsum);
        }
        #pragma unroll
        for (int off = 4; off; off >>= 1) partsum += __shfl_down(partsum, off, 8);
        if (slice == 0) {
            float A = 2.0f * partsum - ls[0] + ((m & 1) ? -ls[2048] : ls[2048]);
            int qp = (2047 * m) & 4095;
            float ang = (float)qp * THETA;
            float gsc = A * (1.0f / 16384.0f);       // 1/(256 pairs)/sqrt(4096)
            out[(size_t)b * 256 + m] = gsc * __cosf(ang);
            out[8192 + (size_t)b * 256 + m] = -gsc * __sinf(ang);
        }
    }
}

extern "C" void kernel_launch(void* const* d_in, const int* in_sizes, int n_in,
                              void* d_out, int out_size, void* d_ws, size_t ws_size,
                              hipStream_t stream) {
    const float* x = (const float*)d_in[0];
    float* out = (float*)d_out;
    float* s = (float*)d_ws;                          // 32*4096 floats (512 KB)
    float* part = s + B_DIM * T_DIM;                  // 32*16*2052 floats (4.2 MB)
    void* args[] = {(void*)&x, (void*)&s, (void*)&part, (void*)&out};
    hipLaunchCooperativeKernel((void*)kfused, dim3(512), dim3(256), args, 0, stream);
}

// Round 9
// 79.197 us; speedup vs baseline: 2.3524x; 2.3524x over previous
//
#include <hip/hip_runtime.h>
#include <hip/hip_bf16.h>

// B=32, T=4096, F=16, L=2047, n=8192, 256 output freqs.
// Math: s[b,t] = sum_f x[b,t,f]; r[b,tau] = sum_t s[t]*s[t+tau] (tau=0..2048)
// G[b,m] = (A[m]/16384) * exp(-2*pi*i*2047*m/4096),
// A[m] = r[0] + 2*sum_{j=1}^{2047} r[j]*cos(2*pi*m*j/4096) + (-1)^m r[2048].
// Output layout (verified R3): PLANAR — Re at [b*256+m], Im at [8192+b*256+m].
// R8 lesson: grid.sync() ~55us/sync on 512 blocks — cooperative fusion loses.
// R9: ksum folded INTO kautoc via redundant window computation (3 nodes -> 2);
//     b = blk&31 keeps a batch's 16 chunk-blocks on one XCD (L2 locality).

#define B_DIM 32
#define T_DIM 4096
#define NLAG 2049
#define NCHUNK 16
#define TS (T_DIM / NCHUNK)            // 256
#define LOGI 2304                      // staged window: max logical idx 2303
#define PSTRIDE 2052                   // partial row stride (16B-aligned)
#define THETA 1.5339807878856412e-03f  // 2*pi/4096

// LDS swizzle: +4 floats pad every 32. Preserves 16B alignment/contiguity for
// l%4==0 accesses; makes stride-8-floats/lane window reads conflict-cheap.
#define SW(l) ((l) + (((l) >> 5) << 2))
#define LS_PHYS 2592                   // SW(2303)=2587

// ---------------- K_A: fused feature-sum + balanced autocorr ----------------
// grid 512; block (b = blk&31, q = blk>>5) stages s[t0 .. t0+2304) by summing
// x features directly (9x redundant vs a separate ksum, but saves a dispatch).
// Then the R7-verified branch-free 32-iteration autocorr body.
__global__ __launch_bounds__(256) void kautoc(const float* __restrict__ x,
                                              float* __restrict__ part) {
    __shared__ __align__(16) float ls[LS_PHYS];
    int tid = threadIdx.x;
    int b = blockIdx.x & 31;                         // same-b blocks -> same XCD
    int q = blockIdx.x >> 5;
    int t0 = q * TS;
    const float4* xb = (const float4*)(x + (size_t)b * T_DIM * 16);
    #pragma unroll
    for (int it = 0; it < LOGI / 256; ++it) {        // 9 points per thread
        int l = it * 256 + tid;
        int g = t0 + l;
        float v = 0.0f;
        if (g < T_DIM) {
            const float4* row = xb + (size_t)g * 4;
            float4 a = row[0], c = row[1], d = row[2], e = row[3];
            v = ((a.x + a.y) + (a.z + a.w)) + ((c.x + c.y) + (c.z + c.w)) +
                ((d.x + d.y) + (d.z + d.w)) + ((e.x + e.y) + (e.z + e.w));
        }
        ls[SW(l)] = v;                               // zero-extended tail
    }
    __syncthreads();

    float* pr = part + ((size_t)b * NCHUNK + q) * PSTRIDE;
    int tau0 = tid * 8;                              // 0..2040

    float acc[8] = {0.f, 0.f, 0.f, 0.f, 0.f, 0.f, 0.f, 0.f};
    float w[16];
    {
        float4 w0 = *(const float4*)&ls[SW(tau0)];
        float4 w1 = *(const float4*)&ls[SW(tau0 + 4)];
        w[0] = w0.x; w[1] = w0.y; w[2] = w0.z; w[3] = w0.w;
        w[4] = w1.x; w[5] = w1.y; w[6] = w1.z; w[7] = w1.w;
    }
    #pragma unroll 4
    for (int t = 0; t < TS; t += 8) {                // 32 uniform iterations
        int ln = t + tau0 + 8;
        float4 n0 = *(const float4*)&ls[SW(ln)];
        float4 n1 = *(const float4*)&ls[SW(ln + 4)];
        w[8] = n0.x;  w[9] = n0.y;  w[10] = n0.z; w[11] = n0.w;
        w[12] = n1.x; w[13] = n1.y; w[14] = n1.z; w[15] = n1.w;
        float4 a0 = *(const float4*)&ls[SW(t)];      // wave-uniform -> broadcast
        float4 a1 = *(const float4*)&ls[SW(t + 4)];
        float as[8] = {a0.x, a0.y, a0.z, a0.w, a1.x, a1.y, a1.z, a1.w};
        #pragma unroll
        for (int s2 = 0; s2 < 8; ++s2) {
            #pragma unroll
            for (int u = 0; u < 8; ++u)
                acc[u] = fmaf(as[s2], w[s2 + u], acc[u]);
        }
        #pragma unroll
        for (int k = 0; k < 8; ++k) w[k] = w[k + 8];
    }
    *(float4*)&pr[tau0]     = make_float4(acc[0], acc[1], acc[2], acc[3]);
    *(float4*)&pr[tau0 + 4] = make_float4(acc[4], acc[5], acc[6], acc[7]);

    // lag 2048: wave 3, branch-free over staged (zero-extended) window
    if (tid >= 192) {
        int sl = tid - 192;
        float a2 = 0.f;
        #pragma unroll
        for (int t = 0; t < TS; t += 64)
            a2 += ls[SW(t + sl)] * ls[SW(t + sl + 2048)];
        for (int off = 32; off; off >>= 1) a2 += __shfl_down(a2, off, 64);
        if (tid == 192) pr[2048] = a2;
    }
}

// ---------------- K_B: fused partial-reduce + LDS-staged DFT ----------------
// grid (32,8); block (b,g): lr[tau] = sum_q part[b][q][tau], then 32 m's
// per block (8 lanes per m over j-slices).
__global__ __launch_bounds__(256) void kdft(const float* __restrict__ part,
                                            float* __restrict__ out) {
    __shared__ float lr[NLAG];
    int b = blockIdx.x;
    const float* pb = part + (size_t)b * NCHUNK * PSTRIDE;
    for (int idx = threadIdx.x; idx < 512; idx += 256) {   // tau 0..2047 as float4
        float4 acc = make_float4(0.f, 0.f, 0.f, 0.f);
        #pragma unroll
        for (int q = 0; q < NCHUNK; ++q) {
            float4 v = *(const float4*)&pb[(size_t)q * PSTRIDE + idx * 4];
            acc.x += v.x; acc.y += v.y; acc.z += v.z; acc.w += v.w;
        }
        *(float4*)&lr[idx * 4] = acc;
    }
    if (threadIdx.x == 0) {                          // tau = 2048
        float acc = 0.f;
        #pragma unroll
        for (int q = 0; q < NCHUNK; ++q)
            acc += pb[(size_t)q * PSTRIDE + 2048];
        lr[2048] = acc;
    }
    __syncthreads();

    int m = blockIdx.y * 32 + (threadIdx.x >> 3);
    int slice = threadIdx.x & 7;
    float partsum = 0.0f;
    #pragma unroll 8
    for (int k = 0; k < 256; ++k) {                  // j = slice + 8k in 0..2047
        int j = slice + (k << 3);
        int p = (m * j) & 4095;                      // exact integer phase
        partsum = fmaf(lr[j], __cosf((float)p * THETA), partsum);
    }
    #pragma unroll
    for (int off = 4; off; off >>= 1) partsum += __shfl_down(partsum, off, 8);
    if (slice == 0) {
        float A = 2.0f * partsum - lr[0] + ((m & 1) ? -lr[2048] : lr[2048]);
        int qp = (2047 * m) & 4095;
        float ang = (float)qp * THETA;
        float g = A * (1.0f / 16384.0f);             // 1/(256 pairs)/sqrt(4096)
        out[(size_t)b * 256 + m] = g * __cosf(ang);
        out[8192 + (size_t)b * 256 + m] = -g * __sinf(ang);
    }
}

extern "C" void kernel_launch(void* const* d_in, const int* in_sizes, int n_in,
                              void* d_out, int out_size, void* d_ws, size_t ws_size,
                              hipStream_t stream) {
    const float* x = (const float*)d_in[0];
    float* out = (float*)d_out;
    float* part = (float*)d_ws;                       // 32*16*2052 floats (4.2 MB)
    kautoc<<<dim3(512), dim3(256), 0, stream>>>(x, part);
    kdft<<<dim3(B_DIM, 8), dim3(256), 0, stream>>>(part, out);
}

// Round 10
// 73.776 us; speedup vs baseline: 2.5253x; 1.0735x over previous
//
#include <hip/hip_runtime.h>
#include <hip/hip_bf16.h>

// B=32, T=4096, F=16, L=2047, n=8192, 256 output freqs.
// Math: s[b,t] = sum_f x[b,t,f]; r[b,tau] = sum_t s[t]*s[t+tau] (tau=0..2048)
// G[b,m] = (A[m]/16384) * exp(-2*pi*i*2047*m/4096),
// A[m] = r[0] + 2*sum_{j=1}^{2047} r[j]*cos(2*pi*m*j/4096) + (-1)^m r[2048].
// Output layout (verified R3): PLANAR — Re at [b*256+m], Im at [8192+b*256+m].
// R8/R9 lesson: node count is free (fixed ~27us graph machinery + 41us ws fill);
// only kernel duration matters. R10: kautoc 16-lag tile (LDS B/FMA halved),
// kdft cosine folding (half the cos work).

#define B_DIM 32
#define T_DIM 4096
#define NLAG 2049
#define NCHUNK 16
#define TS 256
#define LOGI 2304                      // staged window: max logical idx 2303
#define PSTRIDE 2052                   // partial row stride (16B-aligned)
#define THETA 1.5339807878856412e-03f  // 2*pi/4096

// LDS swizzle: +4 floats pad every 32. Preserves 16B alignment/contiguity for
// l%4==0 accesses; spreads the 16-float/lane window-read stride over banks.
#define SW(l) ((l) + (((l) >> 5) << 2))
#define LS_PHYS 2592                   // SW(2303)=2587

// ---------------- K1: s[b,t] = sum_f x[b,t,f] ----------------
__global__ __launch_bounds__(256) void ksum(const float* __restrict__ x,
                                            float* __restrict__ s) {
    int i = blockIdx.x * 256 + threadIdx.x;          // 0..131071 = b*4096+t
    const float4* xv = (const float4*)(x + (size_t)i * 16);
    float4 a = xv[0], b = xv[1], c = xv[2], d = xv[3];
    s[i] = ((a.x + a.y) + (a.z + a.w)) + ((b.x + b.y) + (b.z + b.w)) +
           ((c.x + c.y) + (c.z + c.w)) + ((d.x + d.y) + (d.z + d.w));
}

// ---------------- K2: 16-lag register-tiled autocorr ----------------
// grid (32,16); thread (g=tid&127, h=tid>>7): lags [16g,16g+16) over t-half
// [128h, 128h+128) of the chunk. 24-float sliding window; 4 b128 LDS reads
// per 128 FMAs. Halves merged in-block via LDS scratch; branch-free/balanced
// (zero-extended window kills out-of-range products).
__global__ __launch_bounds__(256) void kautoc(const float* __restrict__ s,
                                              float* __restrict__ part) {
    __shared__ __align__(16) float ls[LS_PHYS];
    int tid = threadIdx.x;
    int b = blockIdx.x;
    int q = blockIdx.y;
    int t0 = q * TS;
    const float* sb = s + (size_t)b * T_DIM;
    for (int idx = tid; idx < LOGI / 4; idx += 256) {
        int l = idx * 4;
        int gi = t0 + l;                             // 4-aligned
        float4 v = make_float4(0.f, 0.f, 0.f, 0.f);
        if (gi < T_DIM) v = *(const float4*)&sb[gi];
        *(float4*)&ls[SW(l)] = v;                    // zero-extended tail
    }
    __syncthreads();

    int g = tid & 127;
    int h = tid >> 7;                                // wave-uniform
    int tau0 = g * 16;                               // 0..2032
    int tb = h * 128;

    float acc[16];
    #pragma unroll
    for (int u = 0; u < 16; ++u) acc[u] = 0.f;
    float w[24];
    {
        int l0 = tb + tau0;                          // multiple of 16
        float4 w0 = *(const float4*)&ls[SW(l0)];
        float4 w1 = *(const float4*)&ls[SW(l0 + 4)];
        float4 w2 = *(const float4*)&ls[SW(l0 + 8)];
        float4 w3 = *(const float4*)&ls[SW(l0 + 12)];
        w[0] = w0.x;  w[1] = w0.y;  w[2] = w0.z;  w[3] = w0.w;
        w[4] = w1.x;  w[5] = w1.y;  w[6] = w1.z;  w[7] = w1.w;
        w[8] = w2.x;  w[9] = w2.y;  w[10] = w2.z; w[11] = w2.w;
        w[12] = w3.x; w[13] = w3.y; w[14] = w3.z; w[15] = w3.w;
    }
    #pragma unroll 2
    for (int it = 0; it < 16; ++it) {                // 16 uniform iterations
        int t = tb + it * 8;
        int ln = t + tau0 + 16;                      // multiple of 8
        float4 n0 = *(const float4*)&ls[SW(ln)];
        float4 n1 = *(const float4*)&ls[SW(ln + 4)];
        w[16] = n0.x; w[17] = n0.y; w[18] = n0.z; w[19] = n0.w;
        w[20] = n1.x; w[21] = n1.y; w[22] = n1.z; w[23] = n1.w;
        float4 a0 = *(const float4*)&ls[SW(t)];      // wave-uniform -> broadcast
        float4 a1 = *(const float4*)&ls[SW(t + 4)];
        float as[8] = {a0.x, a0.y, a0.z, a0.w, a1.x, a1.y, a1.z, a1.w};
        #pragma unroll
        for (int s2 = 0; s2 < 8; ++s2) {
            #pragma unroll
            for (int u = 0; u < 16; ++u)
                acc[u] = fmaf(as[s2], w[s2 + u], acc[u]);
        }
        #pragma unroll
        for (int k = 0; k < 16; ++k) w[k] = w[k + 8];
    }

    // lag 2048 partial (wave 3 reads swizzled ls BEFORE scratch overwrite)
    float a2 = 0.f;
    if (tid >= 192) {
        int sl = tid - 192;
        #pragma unroll
        for (int t = 0; t < TS; t += 64)
            a2 += ls[SW(t + sl)] * ls[SW(t + sl + 2048)];
        for (int off = 32; off; off >>= 1) a2 += __shfl_down(a2, off, 64);
    }

    __syncthreads();                                 // all swizzled reads done
    if (h == 1) {                                    // h=1 parks partials in ls
        *(float4*)&ls[tau0]      = make_float4(acc[0], acc[1], acc[2], acc[3]);
        *(float4*)&ls[tau0 + 4]  = make_float4(acc[4], acc[5], acc[6], acc[7]);
        *(float4*)&ls[tau0 + 8]  = make_float4(acc[8], acc[9], acc[10], acc[11]);
        *(float4*)&ls[tau0 + 12] = make_float4(acc[12], acc[13], acc[14], acc[15]);
    }
    __syncthreads();
    float* pr = part + ((size_t)b * NCHUNK + q) * PSTRIDE;
    if (h == 0) {                                    // h=0 merges + stores row
        #pragma unroll
        for (int u = 0; u < 16; ++u) acc[u] += ls[tau0 + u];
        *(float4*)&pr[tau0]      = make_float4(acc[0], acc[1], acc[2], acc[3]);
        *(float4*)&pr[tau0 + 4]  = make_float4(acc[4], acc[5], acc[6], acc[7]);
        *(float4*)&pr[tau0 + 8]  = make_float4(acc[8], acc[9], acc[10], acc[11]);
        *(float4*)&pr[tau0 + 12] = make_float4(acc[12], acc[13], acc[14], acc[15]);
    }
    if (tid == 192) pr[2048] = a2;
}

// ---------------- K3: reduce + folded cosine DFT ----------------
// grid (32,8); block (b,gb): lr = sum_q part rows; se/sd = lr[j] +/- lr[2048-j];
// 32 m's per block, 8 lanes per m over j = 1..1024 (se[1024]=sd[1024]=0).
__global__ __launch_bounds__(256) void kdft(const float* __restrict__ part,
                                            float* __restrict__ out) {
    __shared__ float lr[PSTRIDE];
    __shared__ float se[1026];
    __shared__ float sd[1026];
    int b = blockIdx.x;
    int tid = threadIdx.x;
    const float* pb = part + (size_t)b * NCHUNK * PSTRIDE;
    for (int idx = tid; idx < 513; idx += 256) {     // floats 0..2051 as float4
        float4 acc = make_float4(0.f, 0.f, 0.f, 0.f);
        #pragma unroll
        for (int q = 0; q < NCHUNK; ++q) {           // [2049..2051] are poison-
            float4 v = *(const float4*)&pb[(size_t)q * PSTRIDE + idx * 4];
            acc.x += v.x; acc.y += v.y; acc.z += v.z; acc.w += v.w;
        }                                            // tiny & never read below
        *(float4*)&lr[idx * 4] = acc;
    }
    __syncthreads();
    for (int j = 1 + tid; j < 1024; j += 256) {
        float a = lr[j], c = lr[2048 - j];
        se[j] = a + c;
        sd[j] = a - c;
    }
    if (tid == 0) { se[1024] = 0.f; sd[1024] = 0.f; }
    __syncthreads();

    int m = blockIdx.y * 32 + (tid >> 3);
    int slice = tid & 7;
    const float* arr = (m & 1) ? sd : se;
    float ps = 0.0f;
    #pragma unroll 8
    for (int k = 0; k < 128; ++k) {                  // j = 1+slice+8k in 1..1024
        int j = 1 + slice + (k << 3);
        int p = (m * j) & 4095;                      // exact integer phase
        ps = fmaf(arr[j], __cosf((float)p * THETA), ps);
    }
    #pragma unroll
    for (int off = 4; off; off >>= 1) ps += __shfl_down(ps, off, 8);
    if (slice == 0) {
        float A;
        if (m & 1) {
            A = 2.0f * ps + lr[0] - lr[2048];
        } else {
            float sgn = ((m >> 1) & 1) ? -2.0f : 2.0f;   // 2*cos(pi*m/2)
            A = 2.0f * ps + lr[0] + lr[2048] + sgn * lr[1024];
        }
        int qp = (2047 * m) & 4095;
        float ang = (float)qp * THETA;
        float gg = A * (1.0f / 16384.0f);            // 1/(256 pairs)/sqrt(4096)
        out[(size_t)b * 256 + m] = gg * __cosf(ang);
        out[8192 + (size_t)b * 256 + m] = -gg * __sinf(ang);
    }
}

extern "C" void kernel_launch(void* const* d_in, const int* in_sizes, int n_in,
                              void* d_out, int out_size, void* d_ws, size_t ws_size,
                              hipStream_t stream) {
    const float* x = (const float*)d_in[0];
    float* out = (float*)d_out;
    float* s = (float*)d_ws;                          // 32*4096 floats (512 KB)
    float* part = s + B_DIM * T_DIM;                  // 32*16*2052 floats (4.2 MB)
    ksum<<<dim3(512), dim3(256), 0, stream>>>(x, s);
    kautoc<<<dim3(B_DIM, NCHUNK), dim3(256), 0, stream>>>(s, part);
    kdft<<<dim3(B_DIM, 8), dim3(256), 0, stream>>>(part, out);
}